// Round 9
// baseline (416.042 us; speedup 1.0000x reference)
//
#include <hip/hip_runtime.h>

typedef __attribute__((ext_vector_type(8))) short bf16x8;
typedef __attribute__((ext_vector_type(8))) unsigned short u16x8;
typedef __attribute__((ext_vector_type(4))) float f32x4;

__device__ __forceinline__ unsigned short f2bf(float f) {
    unsigned int u = __float_as_uint(f);
    u += 0x7fffu + ((u >> 16) & 1u);   // RNE
    return (unsigned short)(u >> 16);
}

// ---------------- Kernel 1: row-normalize fp32 -> bf16 ----------------
__global__ __launch_bounds__(256) void normalize_rows(
    const float* __restrict__ X, unsigned short* __restrict__ Y) {
    const int wave = threadIdx.x >> 6;
    const int lane = threadIdx.x & 63;
    const long row = (long)blockIdx.x * 4 + wave;

    const float4* xr = (const float4*)(X + row * 512);
    float4 a = xr[lane * 2];
    float4 b = xr[lane * 2 + 1];

    float s = a.x * a.x + a.y * a.y + a.z * a.z + a.w * a.w
            + b.x * b.x + b.y * b.y + b.z * b.z + b.w * b.w;
#pragma unroll
    for (int off = 32; off; off >>= 1) s += __shfl_xor(s, off, 64);

    const float inv = rsqrtf(s);   // norm ~22.6; eps never binds

    u16x8 o;
    o[0] = f2bf(a.x * inv); o[1] = f2bf(a.y * inv);
    o[2] = f2bf(a.z * inv); o[3] = f2bf(a.w * inv);
    o[4] = f2bf(b.x * inv); o[5] = f2bf(b.y * inv);
    o[6] = f2bf(b.z * inv); o[7] = f2bf(b.w * inv);
    ((u16x8*)(Y + row * 512))[lane] = o;
}

// ---------------- Kernel 2: C = 1 - Y*Y^T, direct-from-global MFMA ----------------
// Y is 8 MB -> L2/L3 resident; LDS staging is pure overhead here (R1-R6
// evidence: stage+drain+barrier dominates, T2/T4 ~null). Each wave streams
// fragments straight from global: per K-step(32) 8x global_load_dwordx4 +
// 16 MFMA; no LDS, no barriers, no drains. 13-bit offset immediates fold
// the whole K-loop onto 8 base addresses. Triangular tiles + mirror write.
__global__ __launch_bounds__(256) void cosdist_gemm_sym(
    const unsigned short* __restrict__ Y, float* __restrict__ out) {
    constexpr int N = 8192, K = 512, BM = 128;
    constexpr int NTI = N / BM;          // 64 tile rows
    constexpr int A2 = 2 * NTI + 1;      // 129

    // ---- triangular decode: p -> (bi, bj), bi <= bj ----
    const int p = blockIdx.x;
    int bi = (int)floorf(((float)A2 - sqrtf((float)(A2 * A2) - 8.0f * (float)p)) * 0.5f);
    while ((bi + 1) * (A2 - (bi + 1)) / 2 <= p) ++bi;
    while (bi * (A2 - bi) / 2 > p) --bi;
    const int bj = bi + (p - bi * (A2 - bi) / 2);
    const int bm = bi * BM;
    const int bn = bj * BM;

    const int tid  = threadIdx.x;
    const int lane = tid & 63;
    const int wave = tid >> 6;
    const int wr = wave >> 1, wc = wave & 1;
    const int frow = lane & 15;
    const int fk   = (lane >> 4) << 3;   // k-chunk 0/8/16/24

    // ---- per-wave fragment base addresses (A: 4 row-tiles, B: 4 col-tiles) ----
    const unsigned short* Ab0 = Y + (size_t)(bm + wr * 64 + frow) * K + fk;
    const unsigned short* Bb0 = Y + (size_t)(bn + wc * 64 + frow) * K + fk;

    f32x4 acc[4][4] = {};

#pragma unroll
    for (int k0 = 0; k0 < K; k0 += 32) {
        bf16x8 af[4], bfv[4];
#pragma unroll
        for (int t = 0; t < 4; ++t) {
            af[t]  = *(const bf16x8*)(Ab0 + (size_t)t * 16 * K + k0);
            bfv[t] = *(const bf16x8*)(Bb0 + (size_t)t * 16 * K + k0);
        }
#pragma unroll
        for (int mt = 0; mt < 4; ++mt)
#pragma unroll
            for (int nt = 0; nt < 4; ++nt)
                acc[mt][nt] = __builtin_amdgcn_mfma_f32_16x16x32_bf16(
                    af[mt], bfv[nt], acc[mt][nt], 0, 0, 0);
    }

    // ---- epilogue (identical to R6): C/D map col=lane&15, row=(lane>>4)*4+r
    const int crow0 = wr * 64 + ((lane >> 4) << 2);
    const int ccol0 = wc * 64 + frow;
    const bool offdiag = (bm != bn);

#pragma unroll
    for (int mt = 0; mt < 4; ++mt)
#pragma unroll
        for (int nt = 0; nt < 4; ++nt) {
            f32x4 v;
#pragma unroll
            for (int r = 0; r < 4; ++r) v[r] = 1.0f - acc[mt][nt][r];
            const int row = bm + crow0 + mt * 16;   // rows row..row+3
            const int col = bn + ccol0 + nt * 16;

            // mirror tile (bj,bi): 16B store; covers diagonal tile exactly once
            *(f32x4*)&out[(size_t)col * N + row] = v;

            if (offdiag) {
#pragma unroll
                for (int r = 0; r < 4; ++r)
                    out[(size_t)(row + r) * N + col] = v[r];
            }
        }
}

extern "C" void kernel_launch(void* const* d_in, const int* in_sizes, int n_in,
                              void* d_out, int out_size, void* d_ws, size_t ws_size,
                              hipStream_t stream) {
    const float* X = (const float*)d_in[0];          // fp32 [N,512]
    float* out = (float*)d_out;                      // fp32 [N,N]
    unsigned short* Y = (unsigned short*)d_ws;       // bf16 [N,512] scratch

    const int D = 512;
    const int N = in_sizes[0] / D;   // 8192

    normalize_rows<<<N / 4, 256, 0, stream>>>(X, Y);

    const int nt = N / 128;                          // 64
    const int ntiles = nt * (nt + 1) / 2;            // 2080 triangular tiles
    cosdist_gemm_sym<<<ntiles, 256, 0, stream>>>(Y, out);
}

// Round 11
// 334.444 us; speedup vs baseline: 1.2440x; 1.2440x over previous
//
#include <hip/hip_runtime.h>

typedef __attribute__((ext_vector_type(8))) short bf16x8;
typedef __attribute__((ext_vector_type(8))) unsigned short u16x8;
typedef __attribute__((ext_vector_type(4))) float f32x4;

__device__ __forceinline__ unsigned short f2bf(float f) {
    unsigned int u = __float_as_uint(f);
    u += 0x7fffu + ((u >> 16) & 1u);   // RNE
    return (unsigned short)(u >> 16);
}

// ---------------- Kernel 1: row-normalize fp32 -> bf16 ----------------
__global__ __launch_bounds__(256) void normalize_rows(
    const float* __restrict__ X, unsigned short* __restrict__ Y) {
    const int wave = threadIdx.x >> 6;
    const int lane = threadIdx.x & 63;
    const long row = (long)blockIdx.x * 4 + wave;

    const float4* xr = (const float4*)(X + row * 512);
    float4 a = xr[lane * 2];
    float4 b = xr[lane * 2 + 1];

    float s = a.x * a.x + a.y * a.y + a.z * a.z + a.w * a.w
            + b.x * b.x + b.y * b.y + b.z * b.z + b.w * b.w;
#pragma unroll
    for (int off = 32; off; off >>= 1) s += __shfl_xor(s, off, 64);

    const float inv = rsqrtf(s);   // norm ~22.6; eps never binds

    u16x8 o;
    o[0] = f2bf(a.x * inv); o[1] = f2bf(a.y * inv);
    o[2] = f2bf(a.z * inv); o[3] = f2bf(a.w * inv);
    o[4] = f2bf(b.x * inv); o[5] = f2bf(b.y * inv);
    o[6] = f2bf(b.z * inv); o[7] = f2bf(b.w * inv);
    ((u16x8*)(Y + row * 512))[lane] = o;
}

// ---------------- Kernel 2: C = 1 - Y*Y^T, 128x128 tri tiles ----------------
// R6 base (best measured: ~128us GEMM portion) with ONE structural change:
// BK=32 DOUBLE-BUFFERED staging (catalog minimum-2-phase). STAGE(k+1) into
// buf^1 is issued BEFORE computing k, so the L3 staging latency (~500-900cy;
// Y=8MB > 4MB per-XCD L2) is covered by the current step's ds_read+MFMA and
// by TLP, instead of being serially exposed as in R6 (stage->drain->compute).
// LDS stays 32KB (same occupancy), barrier count stays 16, op counts and
// k-summation order identical to R6 -> bitwise-identical output.
// Swizzle for 64B rows: chunk c' = c ^ ((row>>1)&3) (conflict-free per
// 16-lane quarter: 8 wrap-slots x 2 lanes). Epilogue uses nontemporal
// stores so 268MB of streaming output writes don't thrash L2's Y panels.
#define GLDS16(g, l)                                                         \
    __builtin_amdgcn_global_load_lds(                                        \
        (const __attribute__((address_space(1))) void*)(g),                  \
        (__attribute__((address_space(3))) void*)(l), 16, 0, 0)

__global__ __launch_bounds__(256) void cosdist_gemm_sym(
    const unsigned short* __restrict__ Y, float* __restrict__ out) {
    constexpr int N = 8192, K = 512, BM = 128, BK = 32;
    constexpr int NTI = N / BM;          // 64 tile rows
    constexpr int A2 = 2 * NTI + 1;      // 129

    __shared__ __align__(16) short As[2][BM * BK];   // 2 x 8KB
    __shared__ __align__(16) short Bs[2][BM * BK];   // 2 x 8KB

    // ---- triangular decode: p -> (bi, bj), bi <= bj ----
    const int p = blockIdx.x;
    int bi = (int)floorf(((float)A2 - sqrtf((float)(A2 * A2) - 8.0f * (float)p)) * 0.5f);
    while ((bi + 1) * (A2 - (bi + 1)) / 2 <= p) ++bi;
    while (bi * (A2 - bi) / 2 > p) --bi;
    const int bj = bi + (p - bi * (A2 - bi) / 2);
    const int bm = bi * BM;
    const int bn = bj * BM;

    const int tid  = threadIdx.x;
    const int lane = tid & 63;
    const int wave = tid >> 6;
    const int wr = wave >> 1, wc = wave & 1;
    const int frow = lane & 15;
    const int fch  = lane >> 4;                    // k-chunk 0..3 (8 shorts each)
    const int rch  = fch ^ ((frow >> 1) & 3);      // swizzled read chunk (t-invariant)

    // ---- staging map: 512 x 16B chunks per matrix per step; thread t handles
    // slots q=t (rows 0-63) and q=t+256 (rows 64-127). Slot q=(row,c') holds
    // global chunk c = c' ^ ((row>>1)&3); LDS dest linear (q*16B).
    const int srow = tid >> 2;                               // 0..63
    const int cs   = (tid & 3) ^ ((tid >> 3) & 3);           // pre-swizzled src chunk
    const unsigned short* Asrc0 = Y + (size_t)(bm + srow) * K + (cs << 3);
    const unsigned short* Asrc1 = Asrc0 + (size_t)64 * K;
    const unsigned short* Bsrc0 = Y + (size_t)(bn + srow) * K + (cs << 3);
    const unsigned short* Bsrc1 = Bsrc0 + (size_t)64 * K;

    // per-lane fragment byte offsets (shorts) within a buffer
    int aoff[4], boff[4];
#pragma unroll
    for (int t = 0; t < 4; ++t) {
        aoff[t] = (wr * 64 + t * 16 + frow) * BK + (rch << 3);
        boff[t] = (wc * 64 + t * 16 + frow) * BK + (rch << 3);
    }

    f32x4 acc[4][4] = {};

    // ---- prologue: stage step 0 into buffer 0 ----
    GLDS16(Asrc0, &As[0][tid * 8]);
    GLDS16(Asrc1, &As[0][2048 + tid * 8]);
    GLDS16(Bsrc0, &Bs[0][tid * 8]);
    GLDS16(Bsrc1, &Bs[0][2048 + tid * 8]);
    __syncthreads();

#pragma unroll 2
    for (int kt = 0; kt < 16; ++kt) {
        const int cur = kt & 1;
        const int nxt = cur ^ 1;

        // STAGE k+1 first (fire-and-forget; drained by end-of-step syncthreads)
        if (kt < 15) {
            const int ko = (kt + 1) << 5;   // shorts
            GLDS16(Asrc0 + ko, &As[nxt][tid * 8]);
            GLDS16(Asrc1 + ko, &As[nxt][2048 + tid * 8]);
            GLDS16(Bsrc0 + ko, &Bs[nxt][tid * 8]);
            GLDS16(Bsrc1 + ko, &Bs[nxt][2048 + tid * 8]);
        }

        bf16x8 af[4], bfv[4];
#pragma unroll
        for (int t = 0; t < 4; ++t) {
            af[t]  = *(const bf16x8*)&As[cur][aoff[t]];
            bfv[t] = *(const bf16x8*)&Bs[cur][boff[t]];
        }
#pragma unroll
        for (int mt = 0; mt < 4; ++mt)
#pragma unroll
            for (int nt = 0; nt < 4; ++nt)
                acc[mt][nt] = __builtin_amdgcn_mfma_f32_16x16x32_bf16(
                    af[mt], bfv[nt], acc[mt][nt], 0, 0, 0);

        __syncthreads();   // drains this step's 4 GLDS (had full step to land)
    }

    // ---- epilogue: C/D map col=lane&15, row=(lane>>4)*4+r; nontemporal ----
    const int crow0 = wr * 64 + (fch << 2);
    const int ccol0 = wc * 64 + frow;
    const bool offdiag = (bm != bn);

#pragma unroll
    for (int mt = 0; mt < 4; ++mt)
#pragma unroll
        for (int nt = 0; nt < 4; ++nt) {
            f32x4 v;
#pragma unroll
            for (int r = 0; r < 4; ++r) v[r] = 1.0f - acc[mt][nt][r];
            const int row = bm + crow0 + mt * 16;   // rows row..row+3
            const int col = bn + ccol0 + nt * 16;

            // mirror tile (bj,bi): 16B store; covers diagonal tile exactly once
            __builtin_nontemporal_store(v, (f32x4*)&out[(size_t)col * N + row]);

            if (offdiag) {
#pragma unroll
                for (int r = 0; r < 4; ++r)
                    __builtin_nontemporal_store(
                        v[r], &out[(size_t)(row + r) * N + col]);
            }
        }
}

extern "C" void kernel_launch(void* const* d_in, const int* in_sizes, int n_in,
                              void* d_out, int out_size, void* d_ws, size_t ws_size,
                              hipStream_t stream) {
    const float* X = (const float*)d_in[0];          // fp32 [N,512]
    float* out = (float*)d_out;                      // fp32 [N,N]
    unsigned short* Y = (unsigned short*)d_ws;       // bf16 [N,512] scratch

    const int D = 512;
    const int N = in_sizes[0] / D;   // 8192

    normalize_rows<<<N / 4, 256, 0, stream>>>(X, Y);

    const int nt = N / 128;                          // 64
    const int ntiles = nt * (nt + 1) / 2;            // 2080 triangular tiles
    cosdist_gemm_sym<<<ntiles, 256, 0, stream>>>(Y, out);
}